// Round 4
// baseline (347.440 us; speedup 1.0000x reference)
//
#include <hip/hip_runtime.h>

// SuperONN1d = implicit GEMM.
//   Stage 1 (xq_prep): shift-lerp + powers -> XQ_T[b][lp][qc] bf16, lp = l+4.
//     xtile 41 cols -> 45.5 KB LDS -> 3 blocks/CU; register-staged coalesced
//     loads (32 in flight/thread) hide HBM latency.
//   Stage 2 (prep_weights): A[co][qc][tap] -> LINEAR per-chunk wa[c][co][kk]
//     bf16 (no swizzle: A is no longer LDS-staged).
//   Stage 3 (gemm) v4: LDS-read-pipe analysis showed 16 b128 reads/chunk/wave
//     (~92 us/CU with 4-way conflicts) > MFMA floor (46.5 us) -> LDS-bound.
//     A fragments now come DIRECTLY from global (wa = 884 KB, L2/L1-hot,
//     every block reads the same chunks) into registers with a 1-deep
//     prefetch across taps. Only B is LDS-staged (per-s resident slice,
//     which keeps HBM fetch at ~56 MB). LDS reads halve to 8/chunk/wave;
//     barriers drop to 2 per s (12/block). 17 KB LDS, ~150 VGPR -> 3 bl/CU.

#define B_    16
#define CIN   128
#define L_    8192
#define COUT  128
#define K_    9
#define QMAX  3
#define KQ    (QMAX * CIN)        // 384
#define KTOT  (K_ * KQ)           // 3456
#define BK    64
#define GUARD 4
#define LROWS (L_ + 2 * GUARD)    // 8200
#define XQOFF (1u << 20)          // XQ at d_ws + 1 MB (A fragments first)
#define XT    41                  // xtile stride (odd -> conflict-free)

typedef __attribute__((ext_vector_type(8)))  short bf16x8;
typedef __attribute__((ext_vector_type(16))) float f32x16;
typedef __attribute__((ext_vector_type(4)))  int   int4v;

__device__ __forceinline__ unsigned short f2bf(float v) {
    union { float f; unsigned u; } cv; cv.f = v;
    unsigned u = cv.u;
    return (unsigned short)((u + 0x7FFFu + ((u >> 16) & 1u)) >> 16);  // RNE
}

// ---- A prep: w[co][qc][tap] -> wa[c][co][kk] linear bf16, k = c*64+kk ----
__global__ __launch_bounds__(256) void prep_weights(
    const float* __restrict__ w, unsigned short* __restrict__ wa)
{
    int g = blockIdx.x * 256 + threadIdx.x;
    if (g >= COUT * KTOT) return;
    const int c   = g >> 13;             // chunk (8192 shorts each)
    const int r   = g & 8191;
    const int co  = r >> 6;
    const int kk  = r & 63;
    const int k   = c * BK + kk;
    const int tap = k / KQ;
    const int qc  = k - tap * KQ;
    wa[g] = f2bf(w[((size_t)co * KQ + qc) * K_ + tap]);
}

// ---- XQ prep: register-staged coalesced loads -> LDS transpose ----
__global__ __launch_bounds__(256, 3) void xq_prep(
    const float* __restrict__ x, const float* __restrict__ shifts,
    unsigned short* __restrict__ xq)
{
    __shared__ float xtile[128 * XT];            // 20,992 B
    __shared__ unsigned short tile[32 * KQ];     // 24,576 B
    const int l0   = blockIdx.x * 32;
    const int b    = blockIdx.y;
    const int tid  = threadIdx.x;
    const int lane = tid & 63;
    const int w    = tid >> 6;
    const float* xb = x + (size_t)b * CIN * L_;

    // stage: row r (r == w mod 4), tile col = lane (<41), global col l0-4+lane
    const int col = l0 - 4 + lane;
    const bool cok = (lane < XT) & (col >= 0) & (col < L_);
    const float* xsrc = xb + col;
    float rv[32];
#pragma unroll
    for (int j = 0; j < 32; ++j)
        rv[j] = cok ? xsrc[(size_t)(j * 4 + w) * L_] : 0.0f;
    if (lane < XT) {
#pragma unroll
        for (int j = 0; j < 32; ++j)
            xtile[(j * 4 + w) * XT + lane] = rv[j];
    }
    __syncthreads();

    // compute: lanes along ci; w1 and floor(shift) constant per ci
    {
        const int ci   = tid & 127;
        const int lgrp = tid >> 7;               // 0..1, 16 ll each
        const float sh = shifts[2 * ci] * 4.0f;  // MAX_SHIFT
        const float fl = floorf(sh);
        const int  ifl = (int)fl;
        const float w1 = sh - fl;
        int c0 = lgrp * 16 + 4 + ifl;            // v0 col for first ll
        float v_prev = xtile[ci * XT + c0];
#pragma unroll
        for (int j = 0; j < 16; ++j) {
            const int ll = lgrp * 16 + j;
            const float v_next = xtile[ci * XT + c0 + 1];
            const float xs = fmaf(w1, v_next - v_prev, v_prev);
            const float x2 = xs * xs;
            const float x3 = x2 * xs;
            tile[ll * KQ + ci]       = f2bf(xs);
            tile[ll * KQ + 128 + ci] = f2bf(x2);
            tile[ll * KQ + 256 + ci] = f2bf(x3);
            v_prev = v_next;
            ++c0;
        }
    }
    __syncthreads();

    // contiguous 24 KB copy out (rows lp = l0+4 .. l0+35)
    const int4v* src = (const int4v*)tile;
    int4v* dst = (int4v*)(xq + ((size_t)b * LROWS + l0 + GUARD) * KQ);
#pragma unroll
    for (int it = 0; it < 6; ++it)
        dst[it * 256 + tid] = src[it * 256 + tid];

    if (blockIdx.x == 0) {          // zero guard rows lp 0..3
        int4v* g0 = (int4v*)(xq + (size_t)b * LROWS * KQ);
        if (tid < 192) g0[tid] = (int4v){0, 0, 0, 0};
    }
    if (blockIdx.x == gridDim.x - 1) {  // zero guard rows lp 8196..8199
        int4v* g1 = (int4v*)(xq + ((size_t)b * LROWS + L_ + GUARD) * KQ);
        if (tid < 192) g1[tid] = (int4v){0, 0, 0, 0};
    }
}

// ---- GEMM v4: A from global->regs (L2-hot), B resident in LDS per s ----
__global__ __launch_bounds__(256, 3) void gemm(
    const unsigned short* __restrict__ wa,   // [54][128][64] linear bf16
    const unsigned short* __restrict__ xq,   // [B_][LROWS][KQ] bf16
    const float*          __restrict__ bias,
    float*                __restrict__ out)
{
    __shared__ __align__(16) unsigned short ldsB[136 * BK];     // 17,408 B

    const int l0   = blockIdx.x * 128;
    const int b    = blockIdx.y;
    const int tid  = threadIdx.x;
    const int lane = tid & 63;
    const int w    = tid >> 6;               // 0..3
    const int cobase = (w >> 1) * 64;
    const int nbase  = (w & 1) * 64;
    const int n5 = lane & 31;
    const int h  = lane >> 5;

    // B DMA lane pattern: lane j -> row (j>>3), slot (j&7)^((j>>3)&7)
    const int bj_row = lane >> 3;
    const size_t bLaneOff = (size_t)bj_row * KQ + (size_t)(((lane & 7) ^ (bj_row & 7)) << 3);

    f32x16 acc[2][2];
#pragma unroll
    for (int i = 0; i < 2; ++i)
#pragma unroll
        for (int j = 0; j < 2; ++j) acc[i][j] = (f32x16){};

    const unsigned short* xqb   = xq + (size_t)b * LROWS * KQ;
    const unsigned short* bbase = xqb + (size_t)l0 * KQ + bLaneOff;
    // per-lane A fragment bases: frag(fi,kc) at afi + c*8192 + kc*16 shorts
    const unsigned short* a0p = wa + (size_t)(cobase + n5) * 64 + h * 8;  // fi=0
    const unsigned short* a1p = a0p + 32 * 64;                            // fi=1

#pragma unroll 1
    for (int s = 0; s < 6; ++s) {
        // stage B column slice s: rows l0..l0+135, cols s*64..s*64+63
        const unsigned short* bsrc = bbase + s * 64;
#pragma unroll
        for (int i = 0; i < 4; ++i) {
            const int g = w * 4 + i;
            __builtin_amdgcn_global_load_lds(
                (const __attribute__((address_space(1))) void*)(bsrc + (size_t)g * 8 * KQ),
                (__attribute__((address_space(3))) void*)((char*)ldsB + g * 1024),
                16, 0, 0);
        }
        if (w == 0)
            __builtin_amdgcn_global_load_lds(
                (const __attribute__((address_space(1))) void*)(bsrc + (size_t)16 * 8 * KQ),
                (__attribute__((address_space(3))) void*)((char*)ldsB + 16 * 1024),
                16, 0, 0);

        // prefetch A fragments for tap 0 (chunk c = s)
        const unsigned short* cp0 = a0p + (size_t)s * 8192;
        const unsigned short* cp1 = a1p + (size_t)s * 8192;
        bf16x8 A0[2][4];
#pragma unroll
        for (int kc = 0; kc < 4; ++kc) {
            A0[0][kc] = *(const bf16x8*)(cp0 + kc * 16);
            A0[1][kc] = *(const bf16x8*)(cp1 + kc * 16);
        }

        __syncthreads();   // B slice resident (drains A regs too - fine)

#pragma unroll 1
        for (int tap = 0; tap < K_; ++tap) {
            bf16x8 A1[2][4];
            if (tap < 8) {   // prefetch next chunk c = (tap+1)*6+s
                const unsigned short* np0 = a0p + (size_t)((tap + 1) * 6 + s) * 8192;
                const unsigned short* np1 = np0 + 32 * 64;
#pragma unroll
                for (int kc = 0; kc < 4; ++kc) {
                    A1[0][kc] = *(const bf16x8*)(np0 + kc * 16);
                    A1[1][kc] = *(const bf16x8*)(np1 + kc * 16);
                }
            }
#pragma unroll
            for (int kc = 0; kc < 4; ++kc) {
                const int br0 = tap + nbase + n5;
                const int ba0 = br0 * 128 + ((((kc << 1) | h) ^ (br0 & 7)) << 4);
                const int ba1 = ba0 + 32 * 128;   // (br0+32)&7 == br0&7
                const bf16x8 b0 = *(const bf16x8*)((const char*)ldsB + ba0);
                const bf16x8 b1 = *(const bf16x8*)((const char*)ldsB + ba1);
                acc[0][0] = __builtin_amdgcn_mfma_f32_32x32x16_bf16(A0[0][kc], b0, acc[0][0], 0, 0, 0);
                acc[0][1] = __builtin_amdgcn_mfma_f32_32x32x16_bf16(A0[0][kc], b1, acc[0][1], 0, 0, 0);
                acc[1][0] = __builtin_amdgcn_mfma_f32_32x32x16_bf16(A0[1][kc], b0, acc[1][0], 0, 0, 0);
                acc[1][1] = __builtin_amdgcn_mfma_f32_32x32x16_bf16(A0[1][kc], b1, acc[1][1], 0, 0, 0);
            }
            if (tap < 8) {
#pragma unroll
                for (int kc = 0; kc < 4; ++kc) {
                    A0[0][kc] = A1[0][kc];
                    A0[1][kc] = A1[1][kc];
                }
            }
        }
        __syncthreads();   // all B reads done before next s's DMA overwrites
    }

    // ---- epilogue: + bias, coalesced stores ----
#pragma unroll
    for (int fi = 0; fi < 2; ++fi)
#pragma unroll
        for (int bj = 0; bj < 2; ++bj)
#pragma unroll
            for (int r = 0; r < 16; ++r) {
                const int co = cobase + fi * 32 + (r & 3) + 8 * (r >> 2) + 4 * h;
                const int l  = l0 + nbase + bj * 32 + n5;
                out[((size_t)(b * COUT + co)) * L_ + l] = acc[fi][bj][r] + bias[co];
            }
}

extern "C" void kernel_launch(void* const* d_in, const int* in_sizes, int n_in,
                              void* d_out, int out_size, void* d_ws, size_t ws_size,
                              hipStream_t stream) {
    const float* x      = (const float*)d_in[0];  // 16*128*8192
    const float* w      = (const float*)d_in[1];  // 128*384*9
    const float* bias   = (const float*)d_in[2];  // 128
    const float* shifts = (const float*)d_in[3];  // 128*2
    float* out = (float*)d_out;

    const size_t need = (size_t)XQOFF + (size_t)B_ * LROWS * KQ * 2;  // ~101.8 MB
    if (ws_size < need) return;   // clean fail instead of OOB corruption

    unsigned short* wa = (unsigned short*)d_ws;                       // 884,736 B
    unsigned short* xq = (unsigned short*)((char*)d_ws + XQOFF);      // 100.76 MB

    const int nw = COUT * KTOT;                                       // 442,368
    prep_weights<<<(nw + 255) / 256, 256, 0, stream>>>(w, wa);

    dim3 gq(L_ / 32, B_);                                             // 256 x 16
    xq_prep<<<gq, 256, 0, stream>>>(x, shifts, xq);

    dim3 gg(L_ / 128, B_);                                            // 64 x 16 = 1024
    gemm<<<gg, 256, 0, stream>>>(wa, xq, bias, out);
}

// Round 6
// 327.113 us; speedup vs baseline: 1.0621x; 1.0621x over previous
//
#include <hip/hip_runtime.h>

// SuperONN1d = fully fused implicit GEMM (xq_prep eliminated).
//   prep_weights: w[co][qc][tap] -> per-chunk XOR-swizzled wa fragments so an
//     identity DMA copy produces a conflict-free LDS A tile (round-2 proven).
//   gemm (fused): per block (128co x 128l), for each s-slice (64 qc = one
//     ci-half at one power q):
//       1. build xs[136 lp][64 ci] f32 in LDS from x directly (coalesced
//          lanes-along-l loads; shift folded into base addr; f32 lerp).
//          xs UNIONS with ldsA (16 KB) - disjoint live ranges, barrier-split.
//       2. stage ldsB (swizzled, same layout round-2's DMA produced) from xs:
//          pow in f32 + RNE f2bf -> bit-identical to the old XQ contents.
//       3. round-2 tap loop verbatim: per chunk A-DMA (global_load_lds) +
//          2 barriers + 16 ds_read_b128 + 16 MFMA.
//   Kills ~160 MB of HBM XQ round-trip + the whole xq_prep kernel (~90 us).
//   LDS 52.8 KB -> 3 blocks/CU. Summation order identical to round 2.
//   LESSON (round 4): A-from-global regs = 32-line gathers, 2x slower; A must
//   stay on the contiguous-DMA path.
//   (Round 5 bench was an infra failure - container acquisition; resubmit.)

#define B_    16
#define CIN   128
#define L_    8192
#define COUT  128
#define K_    9
#define QMAX  3
#define KQ    (QMAX * CIN)        // 384
#define KTOT  (K_ * KQ)           // 3456
#define BK    64

typedef __attribute__((ext_vector_type(8)))  short bf16x8;
typedef __attribute__((ext_vector_type(16))) float f32x16;

__device__ __forceinline__ unsigned short f2bf(float v) {
    union { float f; unsigned u; } cv; cv.f = v;
    unsigned u = cv.u;
    return (unsigned short)((u + 0x7FFFu + ((u >> 16) & 1u)) >> 16);  // RNE
}

// ---- A prep: w[co][qc][tap] -> wa[c][co][slot s8][i], swizzled:
//   LDS 16B-slot (co, s8) must hold elements k = c*64 + (s8 ^ (co&7))*8 + i
__global__ __launch_bounds__(256) void prep_weights(
    const float* __restrict__ w, unsigned short* __restrict__ wa)
{
    int g = blockIdx.x * 256 + threadIdx.x;
    if (g >= COUT * KTOT) return;
    const int c   = g >> 13;             // chunk (8192 shorts each)
    const int r   = g & 8191;
    const int co  = r >> 6;              // row = 64 shorts = 128 B
    const int s8  = (r >> 3) & 7;
    const int i   = r & 7;
    const int kk  = ((s8 ^ (co & 7)) << 3) | i;
    const int k   = c * BK + kk;
    const int tap = k / KQ;
    const int qc  = k - tap * KQ;
    wa[g] = f2bf(w[((size_t)co * KQ + qc) * K_ + tap]);
}

// ---- fused GEMM ----
__global__ __launch_bounds__(256, 3) void gemm(
    const float* __restrict__ x,         // [B_][CIN][L_]
    const float* __restrict__ shifts,    // [CIN][2]
    const unsigned short* __restrict__ wa,   // [54][128][64] swizzled bf16
    const float* __restrict__ bias,
    float* __restrict__ out)
{
    // xs tile [136 lp][65 (64 ci + pad)] f32 = 35,360 B, UNION with ldsA 16 KB
    __shared__ __align__(16) float xsu[136 * 65];
    __shared__ __align__(16) unsigned short ldsB[136 * BK];     // 17,408 B
    unsigned short* const ldsA = (unsigned short*)xsu;

    const int l0   = blockIdx.x * 128;
    const int b    = blockIdx.y;
    const int tid  = threadIdx.x;
    const int lane = tid & 63;
    const int w4   = tid >> 6;               // wave 0..3
    const int cobase = (w4 >> 1) * 64;
    const int nbase  = (w4 & 1) * 64;
    const int n5 = lane & 31;
    const int h  = lane >> 5;

    // loop-invariant A fragment LDS byte addresses (XOR-swizzled)
    int aaddr[2][4];
#pragma unroll
    for (int fi = 0; fi < 2; ++fi)
#pragma unroll
        for (int kc = 0; kc < 4; ++kc) {
            const int ar = cobase + fi * 32 + n5;
            aaddr[fi][kc] = ar * 128 + ((((kc << 1) | h) ^ (ar & 7)) << 4);
        }

    f32x16 acc[2][2];
#pragma unroll
    for (int i = 0; i < 2; ++i)
#pragma unroll
        for (int j = 0; j < 2; ++j) acc[i][j] = (f32x16){};

    const float* xb = x + (size_t)b * CIN * L_;
    const unsigned short* aw = wa + (size_t)(w4 * 4) * 512 + (size_t)lane * 8;

#pragma unroll 1
    for (int s = 0; s < 6; ++s) {
        const int q  = (s >> 1) + 1;         // power for this slice
        const int ch = (s & 1) * 64;         // ci half base

        // ---- 1. build xs[j][rr]: lp = l0+j (j 0..135), ci = ch+rr (rr 0..63)
        //      coalesced: lanes along l; shift folded into load base. ----
#pragma unroll 1
        for (int k0 = 0; k0 < 16; k0 += 4) {
            float v0r[4][3], v1r[4][3], w1a[4];
#pragma unroll
            for (int kk = 0; kk < 4; ++kk) {
                const int rr = (k0 + kk) * 4 + w4;
                const int ci = ch + rr;
                const float sh = shifts[2 * ci] * 4.0f;   // MAX_SHIFT
                const float fl = floorf(sh);
                const int  ifl = (int)fl;
                w1a[kk] = sh - fl;
                const float* xrow = xb + (size_t)ci * L_;
#pragma unroll
                for (int seg = 0; seg < 3; ++seg) {
                    const int j  = seg * 64 + lane;
                    const int g0 = l0 + j - 4 + ifl;      // i0 gather index
                    const bool jok = j < 136;
                    v0r[kk][seg] = (jok && g0     >= 0 && g0     < L_) ? xrow[g0]     : 0.0f;
                    v1r[kk][seg] = (jok && g0 + 1 >= 0 && g0 + 1 < L_) ? xrow[g0 + 1] : 0.0f;
                }
            }
#pragma unroll
            for (int kk = 0; kk < 4; ++kk) {
                const int rr = (k0 + kk) * 4 + w4;
#pragma unroll
                for (int seg = 0; seg < 3; ++seg) {
                    const int j = seg * 64 + lane;
                    const int l = l0 + j - 4;
                    if (j < 136) {
                        float xsv = fmaf(w1a[kk], v1r[kk][seg] - v0r[kk][seg], v0r[kk][seg]);
                        xsv = (l >= 0 && l < L_) ? xsv : 0.0f;   // zeros padding
                        xsu[j * 65 + rr] = xsv;
                    }
                }
            }
        }
        __syncthreads();   // xs visible to all

        // ---- 2. stage ldsB (swizzled) from xs: 136 rows x 8 slots ----
#pragma unroll
        for (int it = 0; it < 5; ++it) {
            const int g = it * 256 + tid;
            if (g < 1088) {
                const int r    = g >> 3;
                const int slot = g & 7;
                const int o    = slot ^ (r & 7);      // global qc-octet index
                const float* src = xsu + r * 65 + o * 8;
                union { bf16x8 v; unsigned short u[8]; } pk;
#pragma unroll
                for (int i = 0; i < 8; ++i) {
                    const float v = src[i];
                    float p = v;
                    if (q >= 2) p *= v;
                    if (q >= 3) p *= v;
                    pk.u[i] = f2bf(p);
                }
                *(bf16x8*)((char*)ldsB + r * 128 + slot * 16) = pk.v;
            }
        }
        __syncthreads();   // ldsB ready; xs reads done (A-DMA may reuse union)

        // ---- 3. tap loop: round-2 verbatim (A via DMA, 2 barriers/chunk) ----
#pragma unroll 1
        for (int tap = 0; tap < K_; ++tap) {
            const int c = tap * 6 + s;
            const unsigned short* agsrc = aw + (size_t)c * 8192;
#pragma unroll
            for (int i = 0; i < 4; ++i)
                __builtin_amdgcn_global_load_lds(
                    (const __attribute__((address_space(1))) void*)(agsrc + i * 512),
                    (__attribute__((address_space(3))) void*)((char*)ldsA + (w4 * 4 + i) * 1024),
                    16, 0, 0);
            __syncthreads();   // A chunk resident
#pragma unroll
            for (int kc = 0; kc < 4; ++kc) {
                const int br0 = tap + nbase + n5;
                const int ba0 = br0 * 128 + ((((kc << 1) | h) ^ (br0 & 7)) << 4);
                const int ba1 = ba0 + 32 * 128;   // (br0+32)&7 == br0&7
                const bf16x8 a0 = *(const bf16x8*)((const char*)ldsA + aaddr[0][kc]);
                const bf16x8 a1 = *(const bf16x8*)((const char*)ldsA + aaddr[1][kc]);
                const bf16x8 b0 = *(const bf16x8*)((const char*)ldsB + ba0);
                const bf16x8 b1 = *(const bf16x8*)((const char*)ldsB + ba1);
                acc[0][0] = __builtin_amdgcn_mfma_f32_32x32x16_bf16(a0, b0, acc[0][0], 0, 0, 0);
                acc[0][1] = __builtin_amdgcn_mfma_f32_32x32x16_bf16(a0, b1, acc[0][1], 0, 0, 0);
                acc[1][0] = __builtin_amdgcn_mfma_f32_32x32x16_bf16(a1, b0, acc[1][0], 0, 0, 0);
                acc[1][1] = __builtin_amdgcn_mfma_f32_32x32x16_bf16(a1, b1, acc[1][1], 0, 0, 0);
            }
            __syncthreads();   // reads done before next DMA / next s's build
        }
    }

    // ---- epilogue: + bias, coalesced stores ----
#pragma unroll
    for (int fi = 0; fi < 2; ++fi)
#pragma unroll
        for (int bj = 0; bj < 2; ++bj)
#pragma unroll
            for (int r = 0; r < 16; ++r) {
                const int co = cobase + fi * 32 + (r & 3) + 8 * (r >> 2) + 4 * h;
                const int l  = l0 + nbase + bj * 32 + n5;
                out[((size_t)(b * COUT + co)) * L_ + l] = acc[fi][bj][r] + bias[co];
            }
}

extern "C" void kernel_launch(void* const* d_in, const int* in_sizes, int n_in,
                              void* d_out, int out_size, void* d_ws, size_t ws_size,
                              hipStream_t stream) {
    const float* x      = (const float*)d_in[0];  // 16*128*8192
    const float* w      = (const float*)d_in[1];  // 128*384*9
    const float* bias   = (const float*)d_in[2];  // 128
    const float* shifts = (const float*)d_in[3];  // 128*2
    float* out = (float*)d_out;

    const size_t need = (size_t)COUT * KTOT * 2;  // 884,736 B (wa only)
    if (ws_size < need) return;   // clean fail instead of OOB corruption

    unsigned short* wa = (unsigned short*)d_ws;

    const int nw = COUT * KTOT;                                       // 442,368
    prep_weights<<<(nw + 255) / 256, 256, 0, stream>>>(w, wa);

    dim3 gg(L_ / 128, B_);                                            // 64 x 16 = 1024
    gemm<<<gg, 256, 0, stream>>>(x, shifts, wa, bias, out);
}

// Round 7
// 241.053 us; speedup vs baseline: 1.4413x; 1.3570x over previous
//
#include <hip/hip_runtime.h>

// SuperONN1d = implicit GEMM, split pipeline (fusion abandoned: round-6 showed
// the fused build serializes ~110 us of VALU inside the MFMA barrier structure
// and re-reads x 6x; fused gemm = 253 us vs split 112+~100).
//   Stage 1 (xq_prep v5): shift-lerp + powers -> XQ_T[b][lp][qc] bf16, lp=l+4.
//     64 l/block (halo redundancy 13% vs 28%), full-wave coalesced loads,
//     36 reg-staged loads/thread, single 37.4 KB LDS tile (stride 73,
//     conflict-free both phases), ONE barrier, direct coalesced 2B stores
//     (no out-tile / copy-out). 4 blocks/CU.
//   Stage 2 (prep_weights): round-2 exact — per-chunk XOR-swizzled fragments
//     so identity DMA -> conflict-free LDS A tile.
//   Stage 3 (gemm): round-2 exact (measured 112 us): s-outer/tap-inner,
//     136x64 B slice resident in LDS per s, per-chunk A DMA + 2 barriers,
//     33.8 KB -> 4 blocks/CU.
//   LESSONS: (r4) A-from-global regs = 32-line gathers, 2x slower — A stays
//   on contiguous DMA. (r3) pipeline surgery that drops blocks/CU loses more
//   than the drains save. (r6) don't serialize elementwise prep into the GEMM.

#define B_    16
#define CIN   128
#define L_    8192
#define COUT  128
#define K_    9
#define QMAX  3
#define KQ    (QMAX * CIN)        // 384
#define KTOT  (K_ * KQ)           // 3456
#define BK    64
#define GUARD 4
#define LROWS (L_ + 2 * GUARD)    // 8200
#define XQOFF (1u << 20)          // XQ at d_ws + 1 MB (A fragments first)
#define XSTR  73                  // xtile stride: 73 = 9 mod 32, coprime -> CF

typedef __attribute__((ext_vector_type(8)))  short bf16x8;
typedef __attribute__((ext_vector_type(16))) float f32x16;
typedef __attribute__((ext_vector_type(4)))  int   int4v;

__device__ __forceinline__ unsigned short f2bf(float v) {
    union { float f; unsigned u; } cv; cv.f = v;
    unsigned u = cv.u;
    return (unsigned short)((u + 0x7FFFu + ((u >> 16) & 1u)) >> 16);  // RNE
}

// ---- A prep: w[co][qc][tap] -> wa[c][co][slot s8][i], swizzled:
//   LDS 16B-slot (co, s8) must hold elements k = c*64 + (s8 ^ (co&7))*8 + i
__global__ __launch_bounds__(256) void prep_weights(
    const float* __restrict__ w, unsigned short* __restrict__ wa)
{
    int g = blockIdx.x * 256 + threadIdx.x;
    if (g >= COUT * KTOT) return;
    const int c   = g >> 13;             // chunk (8192 shorts each)
    const int r   = g & 8191;
    const int co  = r >> 6;              // row = 64 shorts = 128 B
    const int s8  = (r >> 3) & 7;
    const int i   = r & 7;
    const int kk  = ((s8 ^ (co & 7)) << 3) | i;
    const int k   = c * BK + kk;
    const int tap = k / KQ;
    const int qc  = k - tap * KQ;
    wa[g] = f2bf(w[((size_t)co * KQ + qc) * K_ + tap]);
}

// ---- XQ prep v5: 64 l/block, reg-staged loads, 1 barrier, direct stores ----
__global__ __launch_bounds__(256) void xq_prep(
    const float* __restrict__ x, const float* __restrict__ shifts,
    unsigned short* __restrict__ xq)
{
    __shared__ float xtile[128 * XSTR];          // 37,376 B -> 4 blocks/CU
    const int l0   = blockIdx.x * 64;
    const int b    = blockIdx.y;
    const int tid  = threadIdx.x;
    const int lane = tid & 63;
    const int w4   = tid >> 6;
    const float* xb = x + (size_t)b * CIN * L_;

    // ---- phase 1: load 128 rows x 72 cols (global cols l0-4 .. l0+67),
    //      all 36 loads register-staged before any LDS write ----
    float rv[32], rn[4];
    const int gcol = l0 - 4 + lane;                       // main: tile col = lane
    const bool cok = (gcol >= 0) & (gcol < L_);
#pragma unroll
    for (int j = 0; j < 32; ++j) {
        const int r = w4 * 32 + j;
        rv[j] = cok ? xb[(size_t)r * L_ + gcol] : 0.0f;
    }
    const int ncol = l0 + 60 + (tid & 7);                 // halo: tile col 64+(tid&7)
    const bool nok = ncol < L_;                           // ncol >= 0 always
#pragma unroll
    for (int it = 0; it < 4; ++it) {
        const int r = it * 32 + (tid >> 3);
        rn[it] = nok ? xb[(size_t)r * L_ + ncol] : 0.0f;
    }
#pragma unroll
    for (int j = 0; j < 32; ++j)
        xtile[(w4 * 32 + j) * XSTR + lane] = rv[j];
#pragma unroll
    for (int it = 0; it < 4; ++it)
        xtile[(it * 32 + (tid >> 3)) * XSTR + 64 + (tid & 7)] = rn[it];
    __syncthreads();

    // ---- phase 2: lerp + powers, direct coalesced 2B stores ----
    {
        const int ci    = tid & 127;
        const int lhalf = tid >> 7;              // 0..1 (32 ll each)
        const float sh = shifts[2 * ci] * 4.0f;  // MAX_SHIFT
        const float fl = floorf(sh);
        const int  ifl = (int)fl;
        const float w1 = sh - fl;
        int c0 = lhalf * 32 + 4 + ifl;           // tile col of v0 for first j
        unsigned short* orow =
            xq + ((size_t)b * LROWS + l0 + GUARD + lhalf * 32) * KQ + ci;
        float v_prev = xtile[ci * XSTR + c0];
#pragma unroll
        for (int j = 0; j < 32; ++j) {
            const float v_next = xtile[ci * XSTR + c0 + 1];
            const float xs = fmaf(w1, v_next - v_prev, v_prev);
            const float x2 = xs * xs;
            const float x3 = x2 * xs;
            orow[0]   = f2bf(xs);
            orow[128] = f2bf(x2);
            orow[256] = f2bf(x3);
            v_prev = v_next;
            ++c0;
            orow += KQ;
        }
    }

    if (blockIdx.x == 0) {          // zero guard rows lp 0..3
        int4v* g0 = (int4v*)(xq + (size_t)b * LROWS * KQ);
        if (tid < 192) g0[tid] = (int4v){0, 0, 0, 0};
    }
    if (blockIdx.x == gridDim.x - 1) {  // zero guard rows lp 8196..8199
        int4v* g1 = (int4v*)(xq + ((size_t)b * LROWS + L_ + GUARD) * KQ);
        if (tid < 192) g1[tid] = (int4v){0, 0, 0, 0};
    }
}

// ---- GEMM (round-2 exact): s-outer / tap-inner, B resident in LDS ----
__global__ __launch_bounds__(256, 4) void gemm(
    const unsigned short* __restrict__ wa,   // [54][128][64] swizzled bf16
    const unsigned short* __restrict__ xq,   // [B_][LROWS][KQ] bf16
    const float*          __restrict__ bias,
    float*                __restrict__ out)
{
    __shared__ __align__(16) unsigned short ldsA[COUT * BK];  // 16 KB
    __shared__ __align__(16) unsigned short ldsB[136 * BK];   // 17,408 B

    const int l0   = blockIdx.x * 128;
    const int b    = blockIdx.y;
    const int tid  = threadIdx.x;
    const int lane = tid & 63;
    const int w    = tid >> 6;               // 0..3
    const int cobase = (w >> 1) * 64;
    const int nbase  = (w & 1) * 64;
    const int n5 = lane & 31;
    const int h  = lane >> 5;

    // B DMA lane pattern: lane j -> row (j>>3), slot (j&7)^((j>>3)&7)
    const int bj_row = lane >> 3;
    const size_t bLaneOff = (size_t)bj_row * KQ + (size_t)(((lane & 7) ^ (bj_row & 7)) << 3);

    // loop-invariant A fragment LDS byte addresses (XOR-swizzled)
    int aaddr[2][4];
#pragma unroll
    for (int fi = 0; fi < 2; ++fi)
#pragma unroll
        for (int kc = 0; kc < 4; ++kc) {
            const int ar = cobase + fi * 32 + n5;
            aaddr[fi][kc] = ar * 128 + ((((kc << 1) | h) ^ (ar & 7)) << 4);
        }

    f32x16 acc[2][2];
#pragma unroll
    for (int i = 0; i < 2; ++i)
#pragma unroll
        for (int j = 0; j < 2; ++j) acc[i][j] = (f32x16){};

    const unsigned short* xqb   = xq + (size_t)b * LROWS * KQ;
    const unsigned short* bbase = xqb + (size_t)l0 * KQ + bLaneOff;

#pragma unroll 1
    for (int s = 0; s < 6; ++s) {
        // stage B column slice s: rows l0..l0+135, cols s*64..s*64+63
        const unsigned short* bsrc = bbase + s * 64;
#pragma unroll
        for (int i = 0; i < 4; ++i) {
            const int g = w * 4 + i;
            __builtin_amdgcn_global_load_lds(
                (const __attribute__((address_space(1))) void*)(bsrc + (size_t)g * 8 * KQ),
                (__attribute__((address_space(3))) void*)((char*)ldsB + g * 1024),
                16, 0, 0);
        }
        if (w == 0)
            __builtin_amdgcn_global_load_lds(
                (const __attribute__((address_space(1))) void*)(bsrc + (size_t)16 * 8 * KQ),
                (__attribute__((address_space(3))) void*)((char*)ldsB + 16 * 1024),
                16, 0, 0);

#pragma unroll 1
        for (int tap = 0; tap < K_; ++tap) {
            const int c = tap * 6 + s;
            const unsigned short* agsrc = wa + (size_t)c * 8192 + (size_t)(w * 4) * 512 + lane * 8;
#pragma unroll
            for (int i = 0; i < 4; ++i)
                __builtin_amdgcn_global_load_lds(
                    (const __attribute__((address_space(1))) void*)(agsrc + i * 512),
                    (__attribute__((address_space(3))) void*)((char*)ldsA + (w * 4 + i) * 1024),
                    16, 0, 0);
            __syncthreads();   // drains vmcnt(0): A chunk (+B at s-start) resident
#pragma unroll
            for (int kc = 0; kc < 4; ++kc) {
                const int br0 = tap + nbase + n5;
                const int ba0 = br0 * 128 + ((((kc << 1) | h) ^ (br0 & 7)) << 4);
                const int ba1 = ba0 + 32 * 128;   // (br0+32)&7 == br0&7
                const bf16x8 a0 = *(const bf16x8*)((const char*)ldsA + aaddr[0][kc]);
                const bf16x8 a1 = *(const bf16x8*)((const char*)ldsA + aaddr[1][kc]);
                const bf16x8 b0 = *(const bf16x8*)((const char*)ldsB + ba0);
                const bf16x8 b1 = *(const bf16x8*)((const char*)ldsB + ba1);
                acc[0][0] = __builtin_amdgcn_mfma_f32_32x32x16_bf16(a0, b0, acc[0][0], 0, 0, 0);
                acc[0][1] = __builtin_amdgcn_mfma_f32_32x32x16_bf16(a0, b1, acc[0][1], 0, 0, 0);
                acc[1][0] = __builtin_amdgcn_mfma_f32_32x32x16_bf16(a1, b0, acc[1][0], 0, 0, 0);
                acc[1][1] = __builtin_amdgcn_mfma_f32_32x32x16_bf16(a1, b1, acc[1][1], 0, 0, 0);
            }
            __syncthreads();   // all reads done before next chunk's DMA overwrites
        }
    }

    // ---- epilogue: + bias, coalesced stores ----
#pragma unroll
    for (int fi = 0; fi < 2; ++fi)
#pragma unroll
        for (int bj = 0; bj < 2; ++bj)
#pragma unroll
            for (int r = 0; r < 16; ++r) {
                const int co = cobase + fi * 32 + (r & 3) + 8 * (r >> 2) + 4 * h;
                const int l  = l0 + nbase + bj * 32 + n5;
                out[((size_t)(b * COUT + co)) * L_ + l] = acc[fi][bj][r] + bias[co];
            }
}

extern "C" void kernel_launch(void* const* d_in, const int* in_sizes, int n_in,
                              void* d_out, int out_size, void* d_ws, size_t ws_size,
                              hipStream_t stream) {
    const float* x      = (const float*)d_in[0];  // 16*128*8192
    const float* w      = (const float*)d_in[1];  // 128*384*9
    const float* bias   = (const float*)d_in[2];  // 128
    const float* shifts = (const float*)d_in[3];  // 128*2
    float* out = (float*)d_out;

    const size_t need = (size_t)XQOFF + (size_t)B_ * LROWS * KQ * 2;  // ~101.8 MB
    if (ws_size < need) return;   // clean fail instead of OOB corruption

    unsigned short* wa = (unsigned short*)d_ws;                       // 884,736 B
    unsigned short* xq = (unsigned short*)((char*)d_ws + XQOFF);      // 100.76 MB

    const int nw = COUT * KTOT;                                       // 442,368
    prep_weights<<<(nw + 255) / 256, 256, 0, stream>>>(w, wa);

    dim3 gq(L_ / 64, B_);                                             // 128 x 16 = 2048
    xq_prep<<<gq, 256, 0, stream>>>(x, shifts, xq);

    dim3 gg(L_ / 128, B_);                                            // 64 x 16 = 1024
    gemm<<<gg, 256, 0, stream>>>(wa, xq, bias, out);
}